// Round 5
// baseline (141.050 us; speedup 1.0000x reference)
//
#include <hip/hip_runtime.h>

// Per-row token-count histogram:
//   x: (B=1024, S=2048) int32 tokens in [0, 32128)
//   out: (B, V=32128) float32 counts
// Write-BW-bound (131.6 MB out). v2: vocab sliced 4-way -> 4096 blocks of
// 256 threads, 15.7 KiB LDS each => 8 blocks/CU resident; small per-block
// serial phases interleave across blocks so the store pipe never starves.
// Tokens prefetched to registers before LDS zeroing; NT stores for output.
// v2.1: NT store uses clang ext_vector_type (HIP float4 is a class type,
// rejected by __builtin_nontemporal_store).

#define VOCAB 32128
#define SEQ 2048
#define SLICES 4
#define SLICE_V (VOCAB / SLICES)   // 8032 bins per slice
#define SWORDS (SLICE_V / 2)       // 4016 u32 words (two u16 bins each)
#define BLOCK 256

typedef float f32x4 __attribute__((ext_vector_type(4)));

__global__ __launch_bounds__(BLOCK, 8) void hist_slice_kernel(
    const int* __restrict__ x, float* __restrict__ out) {
    // Packed counts: word w holds bins 2w (low u16), 2w+1 (high u16).
    // Max per-bin count = SEQ = 2048 < 65536 -> carry never crosses halves.
    __shared__ unsigned int cnt[SWORDS];

    const int bid   = blockIdx.x;
    const int row   = bid >> 2;        // SLICES = 4
    const int slice = bid & 3;
    const int tid   = threadIdx.x;
    const unsigned base = (unsigned)(slice * SLICE_V);

    // --- Phase 0: prefetch this row's tokens into registers (HBM latency
    // hides under the LDS zeroing below). 2048 tokens / 256 thr = 2x int4.
    const int4* xrow = reinterpret_cast<const int4*>(x + (size_t)row * SEQ);
    int4 t0 = xrow[tid];
    int4 t1 = xrow[tid + BLOCK];

    // --- Phase 1: zero LDS (uint4, 1004 x 16B / 256 thr ~ 4 iters) ---
    uint4* c4 = reinterpret_cast<uint4*>(cnt);
    for (int i = tid; i < SWORDS / 4; i += BLOCK) {
        c4[i] = make_uint4(0u, 0u, 0u, 0u);
    }
    __syncthreads();

    // --- Phase 2: scatter tokens belonging to this slice ---
    {
        unsigned b;
        b = (unsigned)t0.x - base; if (b < SLICE_V) atomicAdd(&cnt[b >> 1], 1u << ((b & 1) * 16));
        b = (unsigned)t0.y - base; if (b < SLICE_V) atomicAdd(&cnt[b >> 1], 1u << ((b & 1) * 16));
        b = (unsigned)t0.z - base; if (b < SLICE_V) atomicAdd(&cnt[b >> 1], 1u << ((b & 1) * 16));
        b = (unsigned)t0.w - base; if (b < SLICE_V) atomicAdd(&cnt[b >> 1], 1u << ((b & 1) * 16));
        b = (unsigned)t1.x - base; if (b < SLICE_V) atomicAdd(&cnt[b >> 1], 1u << ((b & 1) * 16));
        b = (unsigned)t1.y - base; if (b < SLICE_V) atomicAdd(&cnt[b >> 1], 1u << ((b & 1) * 16));
        b = (unsigned)t1.z - base; if (b < SLICE_V) atomicAdd(&cnt[b >> 1], 1u << ((b & 1) * 16));
        b = (unsigned)t1.w - base; if (b < SLICE_V) atomicAdd(&cnt[b >> 1], 1u << ((b & 1) * 16));
    }
    __syncthreads();

    // --- Phase 3: expand u16 -> f32, coalesced non-temporal 16B stores.
    // Slice offset = slice*8032 floats = 32128 B (16B-aligned). 2008 x f32x4
    // per slice / 256 thr ~ 8 iters.
    float* orow = out + (size_t)row * VOCAB + base;
    const uint2* c2 = reinterpret_cast<const uint2*>(cnt);
    for (int i = tid; i < SWORDS / 2; i += BLOCK) {
        uint2 w = c2[i];
        f32x4 f;
        f.x = (float)(w.x & 0xFFFFu);
        f.y = (float)(w.x >> 16);
        f.z = (float)(w.y & 0xFFFFu);
        f.w = (float)(w.y >> 16);
        __builtin_nontemporal_store(f, reinterpret_cast<f32x4*>(orow) + i);
    }
}

extern "C" void kernel_launch(void* const* d_in, const int* in_sizes, int n_in,
                              void* d_out, int out_size, void* d_ws, size_t ws_size,
                              hipStream_t stream) {
    const int* x = (const int*)d_in[0];
    float* out = (float*)d_out;
    const int B = in_sizes[0] / SEQ;  // 1024
    hipLaunchKernelGGL(hist_slice_kernel, dim3(B * SLICES), dim3(BLOCK), 0, stream, x, out);
}